// Round 1
// 275.710 us; speedup vs baseline: 1.0232x; 1.0232x over previous
//
#include <hip/hip_runtime.h>

// ---------- types ----------
typedef __attribute__((ext_vector_type(8))) short short8;     // 8 bf16 (4 VGPRs)
typedef __attribute__((ext_vector_type(4))) float floatx4;    // MFMA C/D
typedef __attribute__((ext_vector_type(4))) unsigned int uintx4;

// ---------- fp32 -> packed bf16x2 (RNE) ----------
#if __has_builtin(__builtin_amdgcn_cvt_pk_bf16_f32)
typedef __attribute__((ext_vector_type(2))) __bf16 bf16x2;
__device__ __forceinline__ unsigned int pk_bf16(float a, float b) {
  bf16x2 v = __builtin_amdgcn_cvt_pk_bf16_f32(a, b);
  return __builtin_bit_cast(unsigned int, v);
}
#else
__device__ __forceinline__ unsigned int bf16_1(float f) {
  unsigned int u = __builtin_bit_cast(unsigned int, f);
  return (u + 0x7fffu + ((u >> 16) & 1u)) >> 16;
}
__device__ __forceinline__ unsigned int pk_bf16(float a, float b) {
  return bf16_1(a) | (bf16_1(b) << 16);
}
#endif

// Fragment conventions (verified, absmax 3.9e-3):
//   A-frag (16x16x32): lane(ln,quad) holds A[m=ln][k=quad*8+j], j=0..7
//   B-frag:            lane(ln,quad) holds B[n=ln][k=quad*8+j]  (B[k][n]=W[c][r][k], n=r*8+c)
//   C/D:               col=ln, row=quad*4+reg
// Bprep frag id: Fb = ((mod*8 + h)*24 + ks)*4 + nt, n16 = h*4+nt; frag = 64 lanes x 16B.

// ============================================================
// Prepass v2: COALESCED reads (consecutive threads read consecutive 32B of W),
// scatter 16B writes into B-fragment order. Same output layout as before.
// ============================================================
__global__ __launch_bounds__(256) void prep_w(
    const float* __restrict__ Wi, const float* __restrict__ Wc, const float* __restrict__ Wd,
    const float* __restrict__ bi, const float* __restrict__ bc, const float* __restrict__ bd,
    uintx4* __restrict__ Bprep, float* __restrict__ biasPrep) {
  const int t = blockIdx.x * 256 + threadIdx.x;  // 0 .. 147455
  const int mod = t / 49152;                     // 49152 8-float groups per mod
  const int tm = t - mod * 49152;
  const float* __restrict__ W = (mod == 0) ? Wi : ((mod == 1) ? Wc : Wd);

  // coalesced read: 8 consecutive floats at flat index tm*8 of W[mod]
  const float* src = W + (size_t)tm * 8;
  float4 f0 = *(const float4*)(src);
  float4 f1 = *(const float4*)(src + 4);

  // decode (c, r, i=g*8) from flat group index: flat = (c*64 + r)*96 + g
  const int c = tm / 6144;             // 64*96
  const int rem = tm - c * 6144;
  const int r = rem / 96;
  const int g = rem - r * 96;          // i = g*8
  const int ks = g >> 2;               // i >> 5
  const int q = g & 3;                 // (i >> 3) & 3  -> quad
  const int n = r * 8 + c;
  const int n16 = n >> 4;
  const int l = q * 16 + (n & 15);
  const int frag = ((mod * 8 + (n16 >> 2)) * 24 + ks) * 4 + (n16 & 3);

  uintx4 p;
  p.x = pk_bf16(f0.x, f0.y);
  p.y = pk_bf16(f0.z, f0.w);
  p.z = pk_bf16(f1.x, f1.y);
  p.w = pk_bf16(f1.z, f1.w);
  Bprep[(size_t)frag * 64 + l] = p;

  if (t < 1536) {
    const int m2 = t >> 9;
    const int nn = t & 511;
    const float* bb = (m2 == 0) ? bi : ((m2 == 1) ? bc : bd);
    biasPrep[t] = bb[(nn & 7) * 64 + (nn >> 3)];
  }
}

// ============================================================
// Fused v2: 512-thread blocks (8 waves), wave owns n16-range = 1 h (64 cols).
// Same one-shot A staging (48 KB, slot-XOR swizzled), one barrier, then a
// barrier-free 24-step K-loop with DEPTH-2 (3-buffer) prefetch of A and B.
// First two B-step loads issued BEFORE the barrier (no LDS dependency).
// Grid 1536 = 3 mods x 512 m-tiles; 2 blocks/CU -> 16 waves/CU.
// ============================================================
#define LOADA(aa, kk)                                                        \
  {                                                                          \
    _Pragma("unroll") for (int mt = 0; mt < 2; ++mt)                         \
        aa[mt] = Afr[((kk) * 2 + mt) * 64 +                                  \
                     ((ln ^ (((kk) * 4 + quad) & 15)) + (quad << 4))];       \
  }

#define LOADB(bb, kk)                                                        \
  {                                                                          \
    _Pragma("unroll") for (int nt = 0; nt < 4; ++nt)                         \
        bb[nt] = bbase[(size_t)((kk) * 4 + nt) * 64];                        \
  }

#define COMP(aa, bb)                                                     \
  {                                                                      \
    _Pragma("unroll") for (int mt = 0; mt < 2; ++mt)                     \
    {                                                                    \
      short8 af = __builtin_bit_cast(short8, aa[mt]);                    \
      _Pragma("unroll") for (int nt = 0; nt < 4; ++nt)                   \
          acc[mt][nt] = __builtin_amdgcn_mfma_f32_16x16x32_bf16(         \
              af, __builtin_bit_cast(short8, bb[nt]), acc[mt][nt], 0, 0, \
              0);                                                        \
    }                                                                    \
  }

__global__ __launch_bounds__(512, 4) void caps_fused(
    const float* __restrict__ x0, const float* __restrict__ x1, const float* __restrict__ x2,
    const uintx4* __restrict__ Bprep, const float* __restrict__ biasPrep,
    float* __restrict__ out) {
  __shared__ unsigned long long As64[48 * 128];  // 48 frags x 64 slots x 16 B

  const int tid = threadIdx.x;
  const int bx = blockIdx.x;
  const int mod = bx >> 9;           // 1536 = 3 x 512
  const int bm = bx & 511;           // m-tile (32 rows)
  const float* __restrict__ X = (mod == 0) ? x0 : ((mod == 1) ? x1 : x2);

  // ---- one-shot staging: 32 rows x 768 cols fp32, coalesced ----
  const float* src = X + (size_t)bm * 32 * 768;
#pragma unroll
  for (int i = 0; i < 12; ++i) {
    const int idx = i * 2048 + tid * 4;          // flat float index in tile
    float4 f = *(const float4*)(src + idx);
    const int m = (unsigned)idx / 768u;
    const int k = idx - m * 768;
    const int ks = k >> 5;
    const int kk = k & 31;
    const int qk = kk >> 3;                      // quad of k
    const int jh = (kk >> 2) & 1;                // which 8-byte half
    const int mt = m >> 4;
    const int lnn = m & 15;
    const int p = (ks * 4 + qk) & 15;            // slot-XOR spread
    const int slot = (lnn ^ p) + (qk << 4);
    unsigned long long w =
        ((unsigned long long)pk_bf16(f.z, f.w) << 32) | pk_bf16(f.x, f.y);
    As64[(((ks * 2 + mt) * 64 + slot) << 1) + jh] = w;
  }

  const int lane = tid & 63;
  const int ln = lane & 15;
  const int quad = lane >> 4;
  const int wv = tid >> 6;  // wave id 0..7: owns h = wv (n16 = wv*4 + nt)

  const uintx4* Afr = (const uintx4*)As64;
  const uintx4* bbase = Bprep + (size_t)((mod * 8 + wv) * 24) * 4 * 64 + lane;

  floatx4 acc[2][4] = {};
  uintx4 a0[2], a1[2], a2[2], b0[4], b1[4], b2[4];

  // B prefetch for steps 0,1 issued under the barrier drain
  LOADB(b0, 0);
  LOADB(b1, 1);
  __syncthreads();  // the ONLY barrier
  LOADA(a0, 0);
  LOADA(a1, 1);

#pragma unroll 1
  for (int s = 0; s < 21; s += 3) {
    LOADA(a2, s + 2);
    LOADB(b2, s + 2);
    COMP(a0, b0);                    // step s
    LOADA(a0, s + 3);
    LOADB(b0, s + 3);
    COMP(a1, b1);                    // step s+1
    LOADA(a1, s + 4);
    LOADB(b1, s + 4);
    COMP(a2, b2);                    // step s+2
  }
  LOADA(a2, 23);
  LOADB(b2, 23);
  COMP(a0, b0);                      // step 21
  COMP(a1, b1);                      // step 22
  COMP(a2, b2);                      // step 23

  // ---- epilogue: bias + squash (8 consecutive n cols = 8 lanes) + store ----
  const int col0 = mod * 512 + wv * 64 + ln;
  float bias[4];
#pragma unroll
  for (int nt = 0; nt < 4; ++nt) bias[nt] = biasPrep[col0 + nt * 16];

#pragma unroll
  for (int mt = 0; mt < 2; ++mt) {
    const size_t rbase = (size_t)(bm * 32 + mt * 16 + quad * 4) * 1536;
#pragma unroll
    for (int nt = 0; nt < 4; ++nt) {
      float* op = out + rbase + col0 + nt * 16;
#pragma unroll
      for (int jj = 0; jj < 4; ++jj) {
        float u = acc[mt][nt][jj] + bias[nt];
        float s = u * u;
        s += __shfl_xor(s, 1);
        s += __shfl_xor(s, 2);
        s += __shfl_xor(s, 4);
        float sc = s / ((1.0f + s) * sqrtf(s + 1e-7f));
        op[(size_t)jj * 1536] = u * sc;
      }
    }
  }
}

// ============================================================
extern "C" void kernel_launch(void* const* d_in, const int* in_sizes, int n_in,
                              void* d_out, int out_size, void* d_ws, size_t ws_size,
                              hipStream_t stream) {
  const float* ximg = (const float*)d_in[0];
  const float* xcapt = (const float*)d_in[1];
  const float* xdct = (const float*)d_in[2];
  const float* Wi = (const float*)d_in[3];
  const float* bi = (const float*)d_in[4];
  const float* Wc = (const float*)d_in[5];
  const float* bc = (const float*)d_in[6];
  const float* Wd = (const float*)d_in[7];
  const float* bd = (const float*)d_in[8];

  uintx4* Bprep = (uintx4*)d_ws;                           // 2.25 MiB
  float* biasPrep = (float*)((char*)d_ws + 2304 * 1024);   // 6 KiB

  hipLaunchKernelGGL(prep_w, dim3(576), dim3(256), 0, stream,
                     Wi, Wc, Wd, bi, bc, bd, Bprep, biasPrep);
  hipLaunchKernelGGL(caps_fused, dim3(1536), dim3(512), 0, stream,
                     ximg, xcapt, xdct, (const uintx4*)Bprep, biasPrep,
                     (float*)d_out);
}